// Round 5
// baseline (826.457 us; speedup 1.0000x reference)
//
#include <hip/hip_runtime.h>
#include <math.h>

#define PP 7
#define CCH 256
#define CC 4          // channels staged per chunk
#define NSLOT 28      // max staged row slots (14 y-samples x 2 corners)
#define PITCH 128     // floats per staged row (max x-span; levels have W<=128)
#define NWARP 4

// Fractional per-pixel coverage at integer column `colf` of interval [a,b].
__device__ __forceinline__ float coverage(float colf, float a, float b) {
    float af = floorf(a);
    float bc = ceilf(b);
    float v  = (colf >= af && colf < bc) ? 1.0f : 0.0f;
    float wl = (colf == af) ? (1.0f + af - a) : 1.0f;
    float wr = (colf == bc - 1.0f) ? (1.0f + b - bc) : 1.0f;
    return v * wl * wr;
}

__global__ __launch_bounds__(256) void roi_pair_kernel(
    const float* __restrict__ f0, const float* __restrict__ f1,
    const float* __restrict__ f2, const float* __restrict__ f3,
    const float* __restrict__ bh, const float* __restrict__ bo,
    float* __restrict__ out, int K, int NIMG)
{
    const int k    = blockIdx.x;
    const int half = blockIdx.y;   // channels [half*128, half*128+128)
    const int tid  = threadIdx.x;
    const int warp = tid >> 6;
    const int lane = tid & 63;

    __shared__ float rows[CC][NSLOT][PITCH];     // 57344 B staged feature rows
    __shared__ float wbin[49][16];               // per-bin 16 corner weights
    __shared__ int   t_xlo[14], t_xhi[14], t_ylo[14], t_yhi[14];
    __shared__ int   t_xoff_lo[14], t_xoff_hi[14];
    __shared__ float t_wxl[14], t_wxh[14], t_cxu0[14], t_cxu1[14], t_cxo0[14], t_cxo1[14];
    __shared__ int   t_slot_lo[14], t_slot_hi[14];
    __shared__ float t_wyl[14], t_wyh[14], t_cyu0[14], t_cyu1[14], t_cyo0[14], t_cyo1[14];
    __shared__ int   s_rowoff[NSLOT];            // row * W (in floats)
    __shared__ int   s_meta[4];                  // nslot, x0a, spanf4, ov

    // ---- per-box uniform scalar metadata ----
    const float hx1 = bh[k*5+1], hy1 = bh[k*5+2], hx2 = bh[k*5+3], hy2 = bh[k*5+4];
    const float px1 = bo[k*5+1], py1 = bo[k*5+2], px2 = bo[k*5+3], py2 = bo[k*5+4];
    const int   bimg = (int)bh[k*5+0];

    const float ux1 = fminf(hx1, px1), uy1 = fminf(hy1, py1);
    const float ux2 = fmaxf(hx2, px2), uy2 = fmaxf(hy2, py2);
    const float su = sqrtf((ux2-ux1)*(uy2-uy1));
    const float so = sqrtf((px2-px1)*(py2-py1));
    const float s  = fminf(su, so);
    float lvf = floorf(4.0f + log2f(s/224.0f + 1e-6f));
    lvf = fminf(fmaxf(lvf, 2.0f), 5.0f);
    const int lv = (int)lvf - 2;

    const float scales[4] = {0.25f, 0.125f, 0.0625f, 0.03125f};
    const int   dims[4]   = {128, 64, 32, 16};
    const float scale = scales[lv];
    const int   W = dims[lv], H = W;
    const int   HW = W * H;
    const float Wf = (float)W, Hf = (float)H;
    const float* feat = (lv == 0) ? f0 : (lv == 1) ? f1 : (lv == 2) ? f2 : f3;
    const float* plane0 = feat + (size_t)bimg * CCH * HW;

    const float usx1 = ux1*scale, usy1 = uy1*scale, usx2 = ux2*scale, usy2 = uy2*scale;
    const float osx1 = px1*scale, osy1 = py1*scale, osx2 = px2*scale, osy2 = py2*scale;
    const float cux1 = fminf(fmaxf(usx1, 0.f), Wf), cux2 = fminf(fmaxf(usx2, 0.f), Wf);
    const float cuy1 = fminf(fmaxf(usy1, 0.f), Hf), cuy2 = fminf(fmaxf(usy2, 0.f), Hf);
    const float cox1 = fminf(fmaxf(osx1, 0.f), Wf), cox2 = fminf(fmaxf(osx2, 0.f), Wf);
    const float coy1 = fminf(fmaxf(osy1, 0.f), Hf), coy2 = fminf(fmaxf(osy2, 0.f), Hf);
    const float roi_w = fmaxf(usx2 - usx1, 1.0f);
    const float roi_h = fmaxf(usy2 - usy1, 1.0f);

    // ---- P0: raw axis tables (x on wave0 lanes 0..13, y on wave1 lanes 0..13) ----
    if (tid < 14) {
        const int i = tid;
        const float t = (float)(i >> 1) + 0.25f + 0.5f*(float)(i & 1);
        const float p = usx1 + t * (roi_w / 7.0f);
        const float valid = (p >= -1.0f && p <= Wf) ? 1.0f : 0.0f;
        float cc = fmaxf(p, 0.0f);
        const float lo0 = floorf(cc);
        const bool top = (lo0 >= Wf - 1.0f);
        const float lo = top ? (Wf - 1.0f) : lo0;
        const float hi = top ? (Wf - 1.0f) : (lo0 + 1.0f);
        cc = top ? (Wf - 1.0f) : cc;
        const float frac = cc - lo;
        t_xlo[i] = (int)lo;  t_xhi[i] = (int)hi;
        t_wxl[i] = (1.0f - frac) * valid;  t_wxh[i] = frac * valid;
        t_cxu0[i] = coverage(lo, cux1, cux2);
        t_cxu1[i] = coverage(hi, cux1, cux2);
        t_cxo0[i] = coverage(lo, cox1, cox2);
        t_cxo1[i] = coverage(hi, cox1, cox2);
    } else if (tid >= 64 && tid < 78) {
        const int i = tid - 64;
        const float t = (float)(i >> 1) + 0.25f + 0.5f*(float)(i & 1);
        const float p = usy1 + t * (roi_h / 7.0f);
        const float valid = (p >= -1.0f && p <= Hf) ? 1.0f : 0.0f;
        float cc = fmaxf(p, 0.0f);
        const float lo0 = floorf(cc);
        const bool top = (lo0 >= Hf - 1.0f);
        const float lo = top ? (Hf - 1.0f) : lo0;
        const float hi = top ? (Hf - 1.0f) : (lo0 + 1.0f);
        cc = top ? (Hf - 1.0f) : cc;
        const float frac = cc - lo;
        t_ylo[i] = (int)lo;  t_yhi[i] = (int)hi;
        t_wyl[i] = (1.0f - frac) * valid;  t_wyh[i] = frac * valid;
        t_cyu0[i] = coverage(lo, cuy1, cuy2);
        t_cyu1[i] = coverage(hi, cuy1, cuy2);
        t_cyo0[i] = coverage(lo, coy1, coy2);
        t_cyo1[i] = coverage(hi, coy1, coy2);
    }
    __syncthreads();

    // ---- P1: thread 0 derives span, row slots ----
    if (tid == 0) {
        int x0 = 1 << 30, x1 = -1, y0 = 1 << 30, y1 = -1;
        for (int i = 0; i < 14; ++i) {
            x0 = min(x0, t_xlo[i]); x1 = max(x1, t_xhi[i]);
            y0 = min(y0, t_ylo[i]); y1 = max(y1, t_yhi[i]);
        }
        const int x0a = x0 & ~3;
        const int spanf4 = (x1 - x0a + 4) >> 2;       // <= 32
        const int nr = y1 - y0 + 1;
        int nslot;
        if (nr <= NSLOT) {                            // dense: contiguous row range
            nslot = nr;
            for (int j = 0; j < nr; ++j) s_rowoff[j] = (y0 + j) * W;
            for (int i = 0; i < 14; ++i) { t_slot_lo[i] = t_ylo[i] - y0; t_slot_hi[i] = t_yhi[i] - y0; }
        } else {                                      // sparse: 2 slots per y-sample
            nslot = 28;
            for (int i = 0; i < 14; ++i) {
                s_rowoff[2*i]   = t_ylo[i] * W;
                s_rowoff[2*i+1] = t_yhi[i] * W;
                t_slot_lo[i] = 2*i; t_slot_hi[i] = 2*i + 1;
            }
        }
        for (int i = 0; i < 14; ++i) { t_xoff_lo[i] = t_xlo[i] - x0a; t_xoff_hi[i] = t_xhi[i] - x0a; }
        s_meta[0] = nslot; s_meta[1] = x0a; s_meta[2] = spanf4;
        s_meta[3] = (x0a + 4*spanf4 > W) ? 1 : 0;
    }
    __syncthreads();

    const int nslot  = s_meta[0];
    const int x0a    = s_meta[1];
    const int spanf4 = s_meta[2];
    const int ov     = s_meta[3];
    const int danger_blk = ov && (bimg == NIMG - 1);

    // ---- P2: per-bin weights (warp0 lanes 0..48) + per-thread offsets ----
    const int bin = lane;                 // 0..48 active
    const int active = (bin < 49);
    int py = 0, px = 0;
    if (active) { py = bin / 7; px = bin - py * 7; }

    if (warp == 0 && active) {
        #pragma unroll
        for (int isy = 0; isy < 2; ++isy) {
            const int sy = 2*py + isy;
            const float wy0 = t_wyl[sy], wy1 = t_wyh[sy];
            const float yu0 = t_cyu0[sy], yu1 = t_cyu1[sy];
            const float yo0 = t_cyo0[sy], yo1 = t_cyo1[sy];
            #pragma unroll
            for (int isx = 0; isx < 2; ++isx) {
                const int sxm = 2*px + isx;
                const float wx0 = t_wxl[sxm], wx1 = t_wxh[sxm];
                const float xu0 = t_cxu0[sxm], xu1 = t_cxu1[sxm];
                const float xo0 = t_cxo0[sxm], xo1 = t_cxo1[sxm];
                const int p4 = (isy*2 + isx) * 4;
                wbin[bin][p4+0] = wy0*wx0*fmaxf(yu0*xu0, yo0*xo0);
                wbin[bin][p4+1] = wy0*wx1*fmaxf(yu0*xu1, yo0*xo1);
                wbin[bin][p4+2] = wy1*wx0*fmaxf(yu1*xu0, yo1*xo0);
                wbin[bin][p4+3] = wy1*wx1*fmaxf(yu1*xu1, yo1*xo1);
            }
        }
    }

    // per-thread LDS offsets (same every chunk)
    int offs[16];
    if (active) {
        #pragma unroll
        for (int isy = 0; isy < 2; ++isy) {
            const int slo = t_slot_lo[2*py + isy] * PITCH;
            const int shi = t_slot_hi[2*py + isy] * PITCH;
            #pragma unroll
            for (int isx = 0; isx < 2; ++isx) {
                const int xl = t_xoff_lo[2*px + isx];
                const int xh = t_xoff_hi[2*px + isx];
                const int p4 = (isy*2 + isx) * 4;
                offs[p4+0] = slo + xl;
                offs[p4+1] = slo + xh;
                offs[p4+2] = shi + xl;
                offs[p4+3] = shi + xh;
            }
        }
    } else {
        #pragma unroll
        for (int q = 0; q < 16; ++q) offs[q] = 0;
    }
    __syncthreads();

    float wreg[16];
    {
        const float4* wp = (const float4*)&wbin[active ? bin : 0][0];
        #pragma unroll
        for (int q = 0; q < 4; ++q) {
            const float4 v = wp[q];
            wreg[4*q+0] = v.x; wreg[4*q+1] = v.y; wreg[4*q+2] = v.z; wreg[4*q+3] = v.w;
        }
    }

    const float* rbase = &rows[warp][0][0];
    const int items = nslot * CC;
    const int lastRowOff = (H - 1) * W;

    // ---- chunk loop: 32 chunks of 4 channels ----
    for (int it = 0; it < CCH / (2*CC); ++it) {
        const int gc0 = half * (CCH/2) + it * CC;

        // stage rows into LDS (coalesced along x, float4)
        for (int item = warp; item < items; item += NWARP) {
            const int cc2 = item & (CC - 1);
            const int j   = item >> 2;
            const int gc  = gc0 + cc2;
            const float* src = plane0 + (size_t)gc * HW + s_rowoff[j] + x0a;
            if (lane < spanf4) {
                float4 v;
                if (danger_blk && (gc == CCH - 1) && (s_rowoff[j] == lastRowOff) && (lane == spanf4 - 1)) {
                    v.x = v.y = v.z = v.w = 0.0f;
                    const int xb = x0a + 4*lane;
                    const float* sp = src + 4*lane;
                    if (xb + 0 < W) v.x = sp[0];
                    if (xb + 1 < W) v.y = sp[1];
                    if (xb + 2 < W) v.z = sp[2];
                    if (xb + 3 < W) v.w = sp[3];
                } else {
                    v = *(const float4*)(src + 4*lane);
                }
                *(float4*)&rows[cc2][j][4*lane] = v;
            }
        }
        __syncthreads();

        // compute: thread (warp=cc, lane=bin)
        if (active) {
            float acc = 0.0f;
            #pragma unroll
            for (int p = 0; p < 4; ++p) {
                acc += wreg[4*p+0] * rbase[offs[4*p+0]];
                acc += wreg[4*p+1] * rbase[offs[4*p+1]];
                acc += wreg[4*p+2] * rbase[offs[4*p+2]];
                acc += wreg[4*p+3] * rbase[offs[4*p+3]];
            }
            out[(size_t)k * (CCH * PP * PP) + (size_t)(gc0 + warp) * (PP * PP) + bin] = acc * 0.25f;
        }
        __syncthreads();
    }
}

extern "C" void kernel_launch(void* const* d_in, const int* in_sizes, int n_in,
                              void* d_out, int out_size, void* d_ws, size_t ws_size,
                              hipStream_t stream) {
    const float* f0 = (const float*)d_in[0];
    const float* f1 = (const float*)d_in[1];
    const float* f2 = (const float*)d_in[2];
    const float* f3 = (const float*)d_in[3];
    const float* bh = (const float*)d_in[4];
    const float* bo = (const float*)d_in[5];
    float* out = (float*)d_out;
    const int K = in_sizes[4] / 5;
    const int NIMG = in_sizes[0] / (CCH * 128 * 128);

    dim3 grid(K, 2);
    roi_pair_kernel<<<grid, 256, 0, stream>>>(f0, f1, f2, f3, bh, bo, out, K, NIMG);
}

// Round 6
// 146.515 us; speedup vs baseline: 5.6408x; 5.6408x over previous
//
#include <hip/hip_runtime.h>
#include <math.h>

#define PP 7
#define CCH 256

// Fractional per-pixel coverage at integer column `colf` of interval [a,b].
__device__ __forceinline__ float coverage(float colf, float a, float b) {
    float af = floorf(a);
    float bc = ceilf(b);
    float v  = (colf >= af && colf < bc) ? 1.0f : 0.0f;
    float wl = (colf == af) ? (1.0f + af - a) : 1.0f;
    float wr = (colf == bc - 1.0f) ? (1.0f + b - bc) : 1.0f;
    return v * wl * wr;
}

// ---------------- NCHW -> NHWC transpose (per level) ----------------
// src: [N][256][HW] -> dst: [N][HW][256]. HW multiple of 64.
// grid: (HW/64, 4, N), block 256. LDS-tiled, coalesced both sides.
__global__ __launch_bounds__(256) void nchw_to_nhwc(const float* __restrict__ src,
                                                    float* __restrict__ dst, int HW)
{
    __shared__ float tile[64][65];
    const int tx = threadIdx.x & 63, ty = threadIdx.x >> 6;
    const int pix0 = blockIdx.x * 64;
    const int c0   = blockIdx.y * 64;
    const int n    = blockIdx.z;

    const float* s = src + ((size_t)n * CCH + c0) * HW + pix0;
    #pragma unroll
    for (int i = 0; i < 16; ++i) {
        const int r = i*4 + ty;                    // channel within block
        tile[r][tx] = s[(size_t)r * HW + tx];      // lanes contiguous in x
    }
    __syncthreads();
    float* d = dst + ((size_t)n * HW + pix0) * CCH + c0;
    #pragma unroll
    for (int i = 0; i < 16; ++i) {
        const int p = i*4 + ty;                    // pixel within tile
        d[(size_t)p * CCH + tx] = tile[tx][p];     // lanes contiguous in c
    }
}

// ---------------- gather from NHWC (flat, barrier-free hot loop) ----------------
__global__ __launch_bounds__(256) void roi_gather_nhwc(
    const float* __restrict__ n0, const float* __restrict__ n1,
    const float* __restrict__ n2, const float* __restrict__ n3,
    const float* __restrict__ bh, const float* __restrict__ bo,
    float* __restrict__ out, int K)
{
    const int k  = blockIdx.x;   // box pair
    const int py = blockIdx.y;   // output bin row 0..6
    const int c  = threadIdx.x;  // channel

    __shared__ int   t_xoff_lo[14], t_xoff_hi[14];          // x*256
    __shared__ float t_wxl[14], t_wxh[14];
    __shared__ float t_cxu0[14], t_cxu1[14], t_cxo0[14], t_cxo1[14];
    __shared__ int   s_yoff_lo[2], s_yoff_hi[2];            // y*W*256
    __shared__ float s_wyl[2], s_wyh[2];
    __shared__ float s_cyu0[2], s_cyu1[2], s_cyo0[2], s_cyo1[2];

    // ---- per-box uniform scalar metadata ----
    const float hx1 = bh[k*5+1], hy1 = bh[k*5+2], hx2 = bh[k*5+3], hy2 = bh[k*5+4];
    const float px1 = bo[k*5+1], py1 = bo[k*5+2], px2 = bo[k*5+3], py2 = bo[k*5+4];
    const int   bimg = (int)bh[k*5+0];

    const float ux1 = fminf(hx1, px1), uy1 = fminf(hy1, py1);
    const float ux2 = fmaxf(hx2, px2), uy2 = fmaxf(hy2, py2);
    const float su = sqrtf((ux2-ux1)*(uy2-uy1));
    const float so = sqrtf((px2-px1)*(py2-py1));
    const float s  = fminf(su, so);
    float lvf = floorf(4.0f + log2f(s/224.0f + 1e-6f));
    lvf = fminf(fmaxf(lvf, 2.0f), 5.0f);
    const int lv = (int)lvf - 2;

    const float scales[4] = {0.25f, 0.125f, 0.0625f, 0.03125f};
    const int   dims[4]   = {128, 64, 32, 16};
    const float scale = scales[lv];
    const int   W = dims[lv], H = W;
    const int   HW = W * H;
    const float Wf = (float)W, Hf = (float)H;
    const float* nh = (lv == 0) ? n0 : (lv == 1) ? n1 : (lv == 2) ? n2 : n3;

    const float usx1 = ux1*scale, usy1 = uy1*scale, usx2 = ux2*scale, usy2 = uy2*scale;
    const float osx1 = px1*scale, osy1 = py1*scale, osx2 = px2*scale, osy2 = py2*scale;
    const float cux1 = fminf(fmaxf(usx1, 0.f), Wf), cux2 = fminf(fmaxf(usx2, 0.f), Wf);
    const float cuy1 = fminf(fmaxf(usy1, 0.f), Hf), cuy2 = fminf(fmaxf(usy2, 0.f), Hf);
    const float cox1 = fminf(fmaxf(osx1, 0.f), Wf), cox2 = fminf(fmaxf(osx2, 0.f), Wf);
    const float coy1 = fminf(fmaxf(osy1, 0.f), Hf), coy2 = fminf(fmaxf(osy2, 0.f), Hf);
    const float roi_w = fmaxf(usx2 - usx1, 1.0f);
    const float roi_h = fmaxf(usy2 - usy1, 1.0f);

    // ---- axis tables (x on wave0 lanes 0..13, y on wave1 lanes 0..1) ----
    if (threadIdx.x < 14) {
        const int i = threadIdx.x;
        const float t = (float)(i >> 1) + 0.25f + 0.5f*(float)(i & 1);
        const float p = usx1 + t * (roi_w / 7.0f);
        const float valid = (p >= -1.0f && p <= Wf) ? 1.0f : 0.0f;
        float cc = fmaxf(p, 0.0f);
        const float lo0 = floorf(cc);
        const bool top = (lo0 >= Wf - 1.0f);
        const float lo = top ? (Wf - 1.0f) : lo0;
        const float hi = top ? (Wf - 1.0f) : (lo0 + 1.0f);
        cc = top ? (Wf - 1.0f) : cc;
        const float frac = cc - lo;
        t_xoff_lo[i] = (int)lo * CCH;  t_xoff_hi[i] = (int)hi * CCH;
        t_wxl[i] = (1.0f - frac) * valid;  t_wxh[i] = frac * valid;
        t_cxu0[i] = coverage(lo, cux1, cux2);
        t_cxu1[i] = coverage(hi, cux1, cux2);
        t_cxo0[i] = coverage(lo, cox1, cox2);
        t_cxo1[i] = coverage(hi, cox1, cox2);
    } else if (threadIdx.x >= 64 && threadIdx.x < 66) {
        const int isy = threadIdx.x - 64;
        const int i = 2*py + isy;
        const float t = (float)(i >> 1) + 0.25f + 0.5f*(float)(i & 1);
        const float p = usy1 + t * (roi_h / 7.0f);
        const float valid = (p >= -1.0f && p <= Hf) ? 1.0f : 0.0f;
        float cc = fmaxf(p, 0.0f);
        const float lo0 = floorf(cc);
        const bool top = (lo0 >= Hf - 1.0f);
        const float lo = top ? (Hf - 1.0f) : lo0;
        const float hi = top ? (Hf - 1.0f) : (lo0 + 1.0f);
        cc = top ? (Hf - 1.0f) : cc;
        const float frac = cc - lo;
        s_yoff_lo[isy] = (int)lo * W * CCH;  s_yoff_hi[isy] = (int)hi * W * CCH;
        s_wyl[isy] = (1.0f - frac) * valid;  s_wyh[isy] = frac * valid;
        s_cyu0[isy] = coverage(lo, cuy1, cuy2);
        s_cyu1[isy] = coverage(hi, cuy1, cuy2);
        s_cyo0[isy] = coverage(lo, coy1, coy2);
        s_cyo1[isy] = coverage(hi, coy1, coy2);
    }
    __syncthreads();

    // ---- gather + accumulate: base + c is lane-contiguous (coalesced) ----
    const float* pb = nh + (size_t)bimg * HW * CCH + c;

    float accs[7] = {0,0,0,0,0,0,0};

    #pragma unroll
    for (int isy = 0; isy < 2; ++isy) {
        const int   yoL = s_yoff_lo[isy], yoH = s_yoff_hi[isy];
        const float wyl = s_wyl[isy], wyh = s_wyh[isy];
        const float cyu0 = s_cyu0[isy], cyu1 = s_cyu1[isy];
        const float cyo0 = s_cyo0[isy], cyo1 = s_cyo1[isy];
        #pragma unroll
        for (int ix = 0; ix < 14; ++ix) {
            const int pxb = ix >> 1;
            const int xoL = t_xoff_lo[ix], xoH = t_xoff_hi[ix];
            const float wxl = t_wxl[ix], wxh = t_wxh[ix];
            const float cxu0 = t_cxu0[ix], cxu1 = t_cxu1[ix];
            const float cxo0 = t_cxo0[ix], cxo1 = t_cxo1[ix];
            const float w00 = wyl*wxl*fmaxf(cyu0*cxu0, cyo0*cxo0);
            const float w01 = wyl*wxh*fmaxf(cyu0*cxu1, cyo0*cxo1);
            const float w10 = wyh*wxl*fmaxf(cyu1*cxu0, cyo1*cxo0);
            const float w11 = wyh*wxh*fmaxf(cyu1*cxu1, cyo1*cxo1);
            const float a00 = pb[yoL + xoL], a01 = pb[yoL + xoH];
            const float a10 = pb[yoH + xoL], a11 = pb[yoH + xoH];
            accs[pxb] += w00*a00 + w01*a01 + w10*a10 + w11*a11;
        }
    }

    float* op = out + ((size_t)k * CCH + c) * (PP * PP) + py * PP;
    #pragma unroll
    for (int pxb = 0; pxb < 7; ++pxb) op[pxb] = accs[pxb] * 0.25f;
}

// ---------------- fallback: measured-good NCHW direct kernel (291 us) ----------------
__global__ __launch_bounds__(256) void roi_pair_kernel(
    const float* __restrict__ f0, const float* __restrict__ f1,
    const float* __restrict__ f2, const float* __restrict__ f3,
    const float* __restrict__ bh, const float* __restrict__ bo,
    float* __restrict__ out, int K)
{
    const int k  = blockIdx.x;
    const int py = blockIdx.y;
    const int c  = threadIdx.x;

    __shared__ int   t_xlo[14], t_xhi[14];
    __shared__ float t_wxl[14], t_wxh[14], t_cxu0[14], t_cxu1[14], t_cxo0[14], t_cxo1[14];
    __shared__ int   s_ylo[2], s_yhi[2];
    __shared__ float s_wyl[2], s_wyh[2], s_cyu0[2], s_cyu1[2], s_cyo0[2], s_cyo1[2];

    const float hx1 = bh[k*5+1], hy1 = bh[k*5+2], hx2 = bh[k*5+3], hy2 = bh[k*5+4];
    const float px1 = bo[k*5+1], py1 = bo[k*5+2], px2 = bo[k*5+3], py2 = bo[k*5+4];
    const int   bimg = (int)bh[k*5+0];

    const float ux1 = fminf(hx1, px1), uy1 = fminf(hy1, py1);
    const float ux2 = fmaxf(hx2, px2), uy2 = fmaxf(hy2, py2);
    const float su = sqrtf((ux2-ux1)*(uy2-uy1));
    const float so = sqrtf((px2-px1)*(py2-py1));
    const float s  = fminf(su, so);
    float lvf = floorf(4.0f + log2f(s/224.0f + 1e-6f));
    lvf = fminf(fmaxf(lvf, 2.0f), 5.0f);
    const int lv = (int)lvf - 2;

    const float scales[4] = {0.25f, 0.125f, 0.0625f, 0.03125f};
    const int   dims[4]   = {128, 64, 32, 16};
    const float scale = scales[lv];
    const int   W = dims[lv], H = W;
    const float Wf = (float)W, Hf = (float)H;
    const float* feat = (lv == 0) ? f0 : (lv == 1) ? f1 : (lv == 2) ? f2 : f3;

    const float usx1 = ux1*scale, usy1 = uy1*scale, usx2 = ux2*scale, usy2 = uy2*scale;
    const float osx1 = px1*scale, osy1 = py1*scale, osx2 = px2*scale, osy2 = py2*scale;
    const float cux1 = fminf(fmaxf(usx1, 0.f), Wf), cux2 = fminf(fmaxf(usx2, 0.f), Wf);
    const float cuy1 = fminf(fmaxf(usy1, 0.f), Hf), cuy2 = fminf(fmaxf(usy2, 0.f), Hf);
    const float cox1 = fminf(fmaxf(osx1, 0.f), Wf), cox2 = fminf(fmaxf(osx2, 0.f), Wf);
    const float coy1 = fminf(fmaxf(osy1, 0.f), Hf), coy2 = fminf(fmaxf(osy2, 0.f), Hf);
    const float roi_w = fmaxf(usx2 - usx1, 1.0f);
    const float roi_h = fmaxf(usy2 - usy1, 1.0f);

    if (threadIdx.x < 14) {
        const int i = threadIdx.x;
        const float t = (float)(i >> 1) + 0.25f + 0.5f*(float)(i & 1);
        const float p = usx1 + t * (roi_w / 7.0f);
        const float valid = (p >= -1.0f && p <= Wf) ? 1.0f : 0.0f;
        float cc = fmaxf(p, 0.0f);
        const float lo0 = floorf(cc);
        const bool top = (lo0 >= Wf - 1.0f);
        const float lo = top ? (Wf - 1.0f) : lo0;
        const float hi = top ? (Wf - 1.0f) : (lo0 + 1.0f);
        cc = top ? (Wf - 1.0f) : cc;
        const float frac = cc - lo;
        t_xlo[i] = (int)lo;  t_xhi[i] = (int)hi;
        t_wxl[i] = (1.0f - frac) * valid;  t_wxh[i] = frac * valid;
        t_cxu0[i] = coverage(lo, cux1, cux2);
        t_cxu1[i] = coverage(hi, cux1, cux2);
        t_cxo0[i] = coverage(lo, cox1, cox2);
        t_cxo1[i] = coverage(hi, cox1, cox2);
    } else if (threadIdx.x >= 64 && threadIdx.x < 66) {
        const int isy = threadIdx.x - 64;
        const int i = 2*py + isy;
        const float t = (float)(i >> 1) + 0.25f + 0.5f*(float)(i & 1);
        const float p = usy1 + t * (roi_h / 7.0f);
        const float valid = (p >= -1.0f && p <= Hf) ? 1.0f : 0.0f;
        float cc = fmaxf(p, 0.0f);
        const float lo0 = floorf(cc);
        const bool top = (lo0 >= Hf - 1.0f);
        const float lo = top ? (Hf - 1.0f) : lo0;
        const float hi = top ? (Hf - 1.0f) : (lo0 + 1.0f);
        cc = top ? (Hf - 1.0f) : cc;
        const float frac = cc - lo;
        s_ylo[isy] = (int)lo;  s_yhi[isy] = (int)hi;
        s_wyl[isy] = (1.0f - frac) * valid;  s_wyh[isy] = frac * valid;
        s_cyu0[isy] = coverage(lo, cuy1, cuy2);
        s_cyu1[isy] = coverage(hi, cuy1, cuy2);
        s_cyo0[isy] = coverage(lo, coy1, coy2);
        s_cyo1[isy] = coverage(hi, coy1, coy2);
    }
    __syncthreads();

    const float* fc = feat + (size_t)(bimg * CCH + c) * (H * W);
    float accs[7] = {0,0,0,0,0,0,0};

    #pragma unroll
    for (int isy = 0; isy < 2; ++isy) {
        const int   ylo = s_ylo[isy], yhi = s_yhi[isy];
        const float wyl = s_wyl[isy], wyh = s_wyh[isy];
        const float cyu0 = s_cyu0[isy], cyu1 = s_cyu1[isy];
        const float cyo0 = s_cyo0[isy], cyo1 = s_cyo1[isy];
        const float* rlo = fc + ylo * W;
        const float* rhi = fc + yhi * W;
        #pragma unroll
        for (int ix = 0; ix < 14; ++ix) {
            const int pxb = ix >> 1;
            const int xlo = t_xlo[ix], xhi = t_xhi[ix];
            const float wxl = t_wxl[ix], wxh = t_wxh[ix];
            const float cxu0 = t_cxu0[ix], cxu1 = t_cxu1[ix];
            const float cxo0 = t_cxo0[ix], cxo1 = t_cxo1[ix];
            const float w00 = wyl*wxl*fmaxf(cyu0*cxu0, cyo0*cxo0);
            const float w01 = wyl*wxh*fmaxf(cyu0*cxu1, cyo0*cxo1);
            const float w10 = wyh*wxl*fmaxf(cyu1*cxu0, cyo1*cxo0);
            const float w11 = wyh*wxh*fmaxf(cyu1*cxu1, cyo1*cxo1);
            accs[pxb] += w00*rlo[xlo] + w01*rlo[xhi] + w10*rhi[xlo] + w11*rhi[xhi];
        }
    }

    float* op = out + ((size_t)k * CCH + c) * (PP * PP) + py * PP;
    #pragma unroll
    for (int pxb = 0; pxb < 7; ++pxb) op[pxb] = accs[pxb] * 0.25f;
}

extern "C" void kernel_launch(void* const* d_in, const int* in_sizes, int n_in,
                              void* d_out, int out_size, void* d_ws, size_t ws_size,
                              hipStream_t stream) {
    const float* f0 = (const float*)d_in[0];
    const float* f1 = (const float*)d_in[1];
    const float* f2 = (const float*)d_in[2];
    const float* f3 = (const float*)d_in[3];
    const float* bh = (const float*)d_in[4];
    const float* bo = (const float*)d_in[5];
    float* out = (float*)d_out;
    const int K = in_sizes[4] / 5;
    const int NIMG = in_sizes[0] / (CCH * 128 * 128);

    // NHWC workspace layout (floats): [L0 | L1 | L2 | L3]
    const size_t hw0 = 128*128, hw1 = 64*64, hw2 = 32*32, hw3 = 16*16;
    const size_t sz0 = (size_t)NIMG * CCH * hw0;
    const size_t sz1 = (size_t)NIMG * CCH * hw1;
    const size_t sz2 = (size_t)NIMG * CCH * hw2;
    const size_t sz3 = (size_t)NIMG * CCH * hw3;
    const size_t need_bytes = (sz0 + sz1 + sz2 + sz3) * sizeof(float);

    if (ws_size >= need_bytes) {
        float* w0 = (float*)d_ws;
        float* w1 = w0 + sz0;
        float* w2 = w1 + sz1;
        float* w3 = w2 + sz2;

        nchw_to_nhwc<<<dim3((int)(hw0/64), 4, NIMG), 256, 0, stream>>>(f0, w0, (int)hw0);
        nchw_to_nhwc<<<dim3((int)(hw1/64), 4, NIMG), 256, 0, stream>>>(f1, w1, (int)hw1);
        nchw_to_nhwc<<<dim3((int)(hw2/64), 4, NIMG), 256, 0, stream>>>(f2, w2, (int)hw2);
        nchw_to_nhwc<<<dim3((int)(hw3/64), 4, NIMG), 256, 0, stream>>>(f3, w3, (int)hw3);

        roi_gather_nhwc<<<dim3(K, PP), CCH, 0, stream>>>(w0, w1, w2, w3, bh, bo, out, K);
    } else {
        roi_pair_kernel<<<dim3(K, PP), CCH, 0, stream>>>(f0, f1, f2, f3, bh, bo, out, K);
    }
}